// Round 15
// baseline (113.911 us; speedup 1.0000x reference)
//
#include <hip/hip_runtime.h>

// LFMA adapter: out = x@W_base^T + b + x @ (alpha * Re(ifft2(scatter(c, mask_idx))))
// Factored: never materialize Delta_W.
//   X[t,k1] = DFT4096(x rows)      (fused_stage1; Hermitian k<=2048, bf16, dot2 phase2)
//   Y[t,k2] = sum_nz c * X[t,k1]   (spmm_col, readlane+dot2 - R13 proven body)
//   out = SCALE*Re(DFT(Y)) + b + sum(part)   (dft_rows_y, dot2 + fused epilogue)
// R15: scatter||gemm fusion kept (gemm independent of bucketing chain; hides under
// scatter). spmm REVERTED to R13 readlane body: R14's uniform-load variant failed to
// compile because loaded entry words live in VGPRs -> row base not provably uniform ->
// "s" constraint on the asm gather unsatisfiable. readlane results are SGPR by
// construction, which is what makes the saddr form legal.
// Bucketing: two-pass LDS-histogram ranking, no global atomics.

#define TWO_PI 6.28318530717958647692f
constexpr int NROW = 128;
constexpr float SCALE_A = 16.0f / 16777216.0f;
constexpr int NCHUNK = 256;
constexpr int KC = 4;

typedef unsigned short ushort_t;
using short8 = __attribute__((ext_vector_type(8))) short;
using f32x4  = __attribute__((ext_vector_type(4))) float;

__device__ __forceinline__ ushort_t f2bf(float f) {
  unsigned u = __float_as_uint(f);
  u = (u + 0x7FFFu + ((u >> 16) & 1u)) >> 16;   // RNE
  return (ushort_t)u;
}
__device__ __forceinline__ unsigned cvtpk(float lo, float hi) {
  unsigned r;
  asm("v_cvt_pk_bf16_f32 %0, %1, %2" : "=v"(r) : "v"(lo), "v"(hi));
  return r;
}
__device__ __forceinline__ float bflo(unsigned u) { return __int_as_float((int)(u << 16)); }
__device__ __forceinline__ float bfhi(unsigned u) { return __int_as_float((int)(u & 0xffff0000u)); }
__device__ __forceinline__ void dot2(float& acc, unsigned a, unsigned b) {
  asm("v_dot2_f32_bf16 %0, %1, %2, %0" : "+v"(acc) : "v"(a), "v"(b));
}
__device__ __forceinline__ void gload_lds16(const void* g, void* l) {
  __builtin_amdgcn_global_load_lds(
      (const __attribute__((address_space(1))) unsigned*)g,
      (__attribute__((address_space(3))) unsigned*)l, 16, 0, 0);
}

// ---------------- stage 1: dft_x (0..255) || count_chunks (256..511) || xcvt (512..639)
__global__ __launch_bounds__(1024) void fused_stage1(const float* __restrict__ x,
                                                     unsigned* __restrict__ XTb,
                                                     const int* __restrict__ idx, int K,
                                                     int chunk, int* __restrict__ cnt,
                                                     ushort_t* __restrict__ xbf) {
  __shared__ __align__(16) char smem[25600];
  const int bx = blockIdx.x, tid = threadIdx.x;
  if (bx >= 512) {                         // ---- xcvt
    int i = (bx - 512) * 1024 + tid;
    float4 v = ((const float4*)x)[i];
    ((uint2*)xbf)[i] = make_uint2(cvtpk(v.x, v.y), cvtpk(v.z, v.w));
    return;
  }
  if (bx < 256) {
    // ---- dft_rows_x: t = bx&127, qi = bx>>7 (k1 residue half)
    float*    xs   = (float*)smem;
    unsigned* bp   = (unsigned*)(smem + 16384);
    float2*   w64f = (float2*)(smem + 24576);
    unsigned* wA   = (unsigned*)(smem + 25088);
    unsigned* wB   = (unsigned*)(smem + 25344);
    const int t = bx & 127, qi = bx >> 7;
    const float* xrow = x + (size_t)t * 4096;
#pragma unroll
    for (int l = 0; l < 4; ++l) xs[tid + 1024 * l] = xrow[tid + 1024 * l];
    if (tid < 64) {
      float s, c; __sincosf(TWO_PI * (float)tid * (1.0f / 64.0f), &s, &c);
      w64f[tid] = make_float2(c, s);
      wA[tid] = cvtpk(c, -s);
      wB[tid] = cvtpk(s, c);
    }
    __syncthreads();
#pragma unroll
    for (int l = 0; l < 2; ++l) {
      int o = tid + 1024 * l, m1 = o >> 5, k1l = o & 31, k1 = qi * 32 + k1l;
      float ar = 0.f, ai = 0.f;
      for (int m2 = 0; m2 < 64; ++m2) {
        float xv = xs[m1 + (m2 << 6)];
        float2 w = w64f[(m2 * k1) & 63];
        ar = fmaf(xv, w.x, ar); ai = fmaf(xv, w.y, ai);
      }
      float s, c; __sincosf((float)(m1 * k1) * (TWO_PI / 4096.0f), &s, &c);
      bp[(m1 << 5) + k1l] = cvtpk(ar * c - ai * s, ar * s + ai * c);
    }
    __syncthreads();
    {
      const int k1l = tid & 31, k2 = tid >> 5;
      const int k = qi * 32 + k1l + (k2 << 6);
      float xr = 0.f, xi = 0.f;
      for (int m1 = 0; m1 < 64; ++m1) {
        unsigned wi = (unsigned)((m1 * k2) & 63);
        unsigned bv = bp[(m1 << 5) + k1l];
        dot2(xr, wA[wi], bv);
        dot2(xi, wB[wi], bv);
      }
      XTb[(size_t)k * NROW + t] = cvtpk(xr, xi);
      if (qi == 0 && tid == 0) {
        float xr2 = 0.f, xi2 = 0.f;
        for (int m1 = 0; m1 < 64; ++m1) {
          float sgn = (m1 & 1) ? -1.f : 1.f;
          unsigned bv = bp[m1 << 5];
          xr2 = fmaf(sgn, bflo(bv), xr2);
          xi2 = fmaf(sgn, bfhi(bv), xi2);
        }
        XTb[(size_t)2048 * NROW + t] = cvtpk(xr2, xi2);
      }
    }
  } else {
    // ---- count_chunks
    int* h = (int*)smem;
    const int c = bx - 256;
#pragma unroll
    for (int l = 0; l < 4; ++l) h[tid + 1024 * l] = 0;
    __syncthreads();
    const int j0 = c * chunk, j1 = min(j0 + chunk, K);
    for (int j = j0 + tid; j < j1; j += 1024) atomicAdd(&h[idx[j] & 4095], 1);
    __syncthreads();
#pragma unroll
    for (int l = 0; l < 4; ++l) cnt[(size_t)c * 4096 + tid + 1024 * l] = h[tid + 1024 * l];
  }
}

// ---------------- S2: per-column exclusive scan over chunks (in place) + totals
__global__ __launch_bounds__(256) void colscan(int* __restrict__ cnt, int* __restrict__ tot) {
  const int k2 = blockIdx.x * 256 + threadIdx.x;
  int run = 0;
  for (int c8 = 0; c8 < NCHUNK; c8 += 8) {
    int v[8];
#pragma unroll
    for (int i = 0; i < 8; ++i) v[i] = cnt[(size_t)(c8 + i) * 4096 + k2];
#pragma unroll
    for (int i = 0; i < 8; ++i) {
      cnt[(size_t)(c8 + i) * 4096 + k2] = run;
      run += v[i];
    }
  }
  tot[k2] = run;
}

// ---------------- B2: exclusive scan over 4096 totals (single block)
__global__ __launch_bounds__(1024) void scan4096(const int* __restrict__ count,
                                                 int* __restrict__ off) {
  __shared__ int s[4096];
  int tid = threadIdx.x;
#pragma unroll
  for (int l = 0; l < 4; ++l) s[tid + 1024 * l] = count[tid + 1024 * l];
  __syncthreads();
  for (int d = 1; d < 4096; d <<= 1) {
    int v[4];
#pragma unroll
    for (int l = 0; l < 4; ++l) {
      int i = tid + 1024 * l;
      v[l] = s[i] + ((i >= d) ? s[i - d] : 0);
    }
    __syncthreads();
#pragma unroll
    for (int l = 0; l < 4; ++l) s[tid + 1024 * l] = v[l];
    __syncthreads();
  }
#pragma unroll
  for (int l = 0; l < 4; ++l) {
    int i = tid + 1024 * l;
    off[i] = s[i] - count[i];
  }
}

// ---------------- scatter (blocks 0..255, 256 thr) || gemm (blocks 256..511)
__global__ __launch_bounds__(256) void scatter_gemm(const int* __restrict__ idx,
                                                    const float* __restrict__ cre,
                                                    const float* __restrict__ cim, int K,
                                                    int chunk, const int* __restrict__ base,
                                                    const int* __restrict__ off,
                                                    uint2* __restrict__ bucket,
                                                    const ushort_t* __restrict__ xbf,
                                                    const float* __restrict__ W,
                                                    ushort_t* __restrict__ partb) {
  __shared__ __align__(16) char smem[32768];
  const int tid = threadIdx.x;
  if (blockIdx.x < 256) {
    // ---------------- scatter (LDS-rank, 256 threads) ----------------
    int* lbase = (int*)smem;
    int* lcur  = (int*)(smem + 16384);
    const int c = blockIdx.x;
#pragma unroll
    for (int l = 0; l < 16; ++l) {
      int k2 = tid + 256 * l;
      lbase[k2] = base[(size_t)c * 4096 + k2] + off[k2];
      lcur[k2] = 0;
    }
    __syncthreads();
    const int j0 = c * chunk, j1 = min(j0 + chunk, K);
    for (int j = j0 + tid; j < j1; j += 256) {
      int p = idx[j];
      int k2 = p & 4095;
      int r = atomicAdd(&lcur[k2], 1);
      unsigned cr = f2bf(cre[j]), ci = f2bf(cim[j]);
      bucket[lbase[k2] + r] = make_uint2((unsigned)(p >> 12) | (cr << 16), ci << 16);
    }
  } else {
    // ---------------- gemm ----------------
    ushort_t* xs = (ushort_t*)smem;         // [128][64] bf16, 16 KB
    float* wsf = (float*)(smem + 16384);    // [64][64] fp32, 16 KB
    const int bg = blockIdx.x - 256;
    const int f0 = (bg & 63) * 64;
    const int kc = bg >> 6;
    const int w = tid >> 6, lane = tid & 63;
    f32x4 acc[2][4];
#pragma unroll
    for (int i = 0; i < 2; ++i)
#pragma unroll
      for (int j = 0; j < 4; ++j) acc[i][j] = (f32x4){0.f, 0.f, 0.f, 0.f};
    const int kbeg = kc * 1024;
    for (int st = 0; st < 16; ++st) {
      const int k0 = kbeg + st * 64;
#pragma unroll
      for (int cc = 0; cc < 4; ++cc) {
        int lb = w * 4096 + cc * 1024;
        int e = (lb >> 1) + lane * 8;
        int r = e >> 6, sl = (e >> 3) & 7;
        gload_lds16(xbf + (size_t)r * 4096 + k0 + ((sl ^ (r & 7)) << 3),
                    (char*)xs + lb);
      }
#pragma unroll
      for (int cc = 0; cc < 4; ++cc) {
        int lb = w * 4096 + cc * 1024;
        int e32 = (lb >> 2) + lane * 4;
        int r = e32 >> 6, g = (e32 >> 2) & 15, s8 = g >> 1, h = g & 1;
        gload_lds16(W + (size_t)(f0 + r) * 4096 + k0 + ((s8 ^ (r & 7)) << 3) + (h << 2),
                    (char*)wsf + lb);
      }
      __syncthreads();
#pragma unroll
      for (int kk = 0; kk < 2; ++kk) {
        int ksA = kk * 4 + (lane >> 4);
        short8 af[2], bfr[4];
#pragma unroll
        for (int mf = 0; mf < 2; ++mf) {
          int ra = w * 32 + mf * 16 + (lane & 15);
          af[mf] = *(const short8*)(&xs[ra * 64 + ((ksA ^ (ra & 7)) << 3)]);
        }
#pragma unroll
        for (int nf = 0; nf < 4; ++nf) {
          int rb = nf * 16 + (lane & 15);
          const float* bpp = &wsf[rb * 64 + ((ksA ^ (rb & 7)) << 3)];
          float4 a4 = *(const float4*)bpp;
          float4 b4 = *(const float4*)(bpp + 4);
          union { uint4 u; short8 s; } pk;
          pk.u.x = cvtpk(a4.x, a4.y);
          pk.u.y = cvtpk(a4.z, a4.w);
          pk.u.z = cvtpk(b4.x, b4.y);
          pk.u.w = cvtpk(b4.z, b4.w);
          bfr[nf] = pk.s;
        }
#pragma unroll
        for (int mf = 0; mf < 2; ++mf)
#pragma unroll
          for (int nf = 0; nf < 4; ++nf)
            acc[mf][nf] = __builtin_amdgcn_mfma_f32_16x16x32_bf16(af[mf], bfr[nf], acc[mf][nf], 0, 0, 0);
      }
      __syncthreads();
    }
    ushort_t* pb = partb + ((size_t)kc << 19);
#pragma unroll
    for (int mf = 0; mf < 2; ++mf)
#pragma unroll
      for (int nf = 0; nf < 4; ++nf)
#pragma unroll
        for (int reg = 0; reg < 4; ++reg) {
          int row = w * 32 + mf * 16 + (lane >> 4) * 4 + reg;
          int col = f0 + nf * 16 + (lane & 15);
          pb[(size_t)row * 4096 + col] = f2bf(acc[mf][nf][reg]);
        }
  }
}

// ---------------- spmm: Y[t][k2] = sum c * X[t,k1] (R13 proven readlane+dot2 body)
__global__ __launch_bounds__(256, 4) void spmm_col(const uint2* __restrict__ bucket,
                                                   const int* __restrict__ off,
                                                   const int* __restrict__ count,
                                                   const unsigned* __restrict__ XTb,
                                                   unsigned* __restrict__ Yp) {
  __shared__ float4 red[2][64];
  const int lane = threadIdx.x & 63;
  const int wid = threadIdx.x >> 6;
  const int colsel = wid >> 1, half = wid & 1;
  const int k2 = blockIdx.x * 2 + colsel;
  const int s = off[k2], n = count[k2];
  const unsigned voff = lane * 8;
  float ar0 = 0.f, ai0 = 0.f, ar1 = 0.f, ai1 = 0.f;
  for (int c = half * 64; c < n; c += 128) {
    int idx = c + lane;
    uint2 ec = (idx < n) ? bucket[s + idx] : make_uint2(0u, 0u);
#pragma unroll
    for (int g = 0; g < 64; g += 8) {
      unsigned Ap[8], Bp[8];
      uint2 xv0, xv1, xv2, xv3, xv4, xv5, xv6, xv7;
#pragma unroll
      for (int u = 0; u < 8; ++u) {
        unsigned w0 = (unsigned)__builtin_amdgcn_readlane((int)ec.x, g + u);
        unsigned w1 = (unsigned)__builtin_amdgcn_readlane((int)ec.y, g + u);
        int k1 = (int)(w0 & 0xfffu);
        unsigned cj = (k1 > 2048) ? 0x8000u : 0u;
        int r = (k1 > 2048) ? 4096 - k1 : k1;
        unsigned cr16 = w0 >> 16;
        unsigned ci16 = w1 >> 16;
        Ap[u] = cr16 | ((ci16 ^ 0x8000u ^ cj) << 16);
        Bp[u] = ci16 | ((cr16 ^ cj) << 16);
        const unsigned* p = XTb + (size_t)r * NROW;
        uint2* dst = (u == 0) ? &xv0 : (u == 1) ? &xv1 : (u == 2) ? &xv2 :
                     (u == 3) ? &xv3 : (u == 4) ? &xv4 : (u == 5) ? &xv5 :
                     (u == 6) ? &xv6 : &xv7;
        asm volatile("global_load_dwordx2 %0, %1, %2"
                     : "=v"(*dst) : "v"(voff), "s"(p) : "memory");
      }
      asm volatile("s_waitcnt vmcnt(0)"
                   : "+v"(xv0), "+v"(xv1), "+v"(xv2), "+v"(xv3),
                     "+v"(xv4), "+v"(xv5), "+v"(xv6), "+v"(xv7) :: "memory");
      __builtin_amdgcn_sched_barrier(0);
#pragma unroll
      for (int u = 0; u < 8; ++u) {
        uint2 xv = (u == 0) ? xv0 : (u == 1) ? xv1 : (u == 2) ? xv2 :
                   (u == 3) ? xv3 : (u == 4) ? xv4 : (u == 5) ? xv5 :
                   (u == 6) ? xv6 : xv7;
        dot2(ar0, Ap[u], xv.x);
        dot2(ai0, Bp[u], xv.x);
        dot2(ar1, Ap[u], xv.y);
        dot2(ai1, Bp[u], xv.y);
      }
    }
  }
  if (half == 1) red[colsel][lane] = make_float4(ar0, ai0, ar1, ai1);
  __syncthreads();
  if (half == 0) {
    float4 o = red[colsel][lane];
    ar0 += o.x; ai0 += o.y; ar1 += o.z; ai1 += o.w;
    Yp[(size_t)(2 * lane) * 4096 + k2]     = cvtpk(ar0, ai0);
    Yp[(size_t)(2 * lane + 1) * 4096 + k2] = cvtpk(ar1, ai1);
  }
}

// ---------------- out = SCALE*Re(DFT(Yp row)) + bias + sum(bf16 partials). grid (128,2).
__global__ __launch_bounds__(1024) void dft_rows_y(const unsigned* __restrict__ Yp,
                                                   const ushort_t* __restrict__ partb,
                                                   const float* __restrict__ bias,
                                                   float* __restrict__ out) {
  __shared__ unsigned ys[4096];
  __shared__ unsigned bp[2048];
  __shared__ unsigned wA[64], wB[64];
  const int t = blockIdx.x, qi = blockIdx.y, tid = threadIdx.x;
  const unsigned* yrow = Yp + (size_t)t * 4096;
#pragma unroll
  for (int l = 0; l < 4; ++l) ys[tid + 1024 * l] = yrow[tid + 1024 * l];
  if (tid < 64) {
    float s, c; __sincosf(TWO_PI * (float)tid * (1.0f / 64.0f), &s, &c);
    wA[tid] = cvtpk(c, -s);
    wB[tid] = cvtpk(s, c);
  }
  __syncthreads();
#pragma unroll
  for (int l = 0; l < 2; ++l) {
    int o = tid + 1024 * l, a = o >> 5, n1l = o & 31, n1 = qi * 32 + n1l;
    float ar = 0.f, ai = 0.f;
    for (int b = 0; b < 64; ++b) {
      unsigned yv = ys[a + (b << 6)];
      unsigned wi = (unsigned)((n1 * b) & 63);
      dot2(ar, wA[wi], yv);
      dot2(ai, wB[wi], yv);
    }
    float s, c; __sincosf((float)(n1 * a) * (TWO_PI / 4096.0f), &s, &c);
    bp[(a << 5) + n1l] = cvtpk(ar * c - ai * s, ar * s + ai * c);
  }
  __syncthreads();
  float* orow = out + (size_t)t * 4096;
  const int n1l = tid & 31;
  const int n1 = qi * 32 + n1l;
#pragma unroll
  for (int l = 0; l < 2; ++l) {
    int n2 = (tid >> 5) + 32 * l;
    float accv = 0.f;
    for (int a = 0; a < 64; ++a)
      dot2(accv, wA[(unsigned)((n2 * a) & 63)], bp[(a << 5) + n1l]);
    int o = n1 + (n2 << 6);
    float sum = accv * SCALE_A + bias[o];
#pragma unroll
    for (int i = 0; i < KC; ++i)
      sum += __int_as_float((int)((unsigned)partb[((size_t)i << 19) + ((size_t)t << 12) + o] << 16));
    orow[o] = sum;
  }
}

extern "C" void kernel_launch(void* const* d_in, const int* in_sizes, int n_in,
                              void* d_out, int out_size, void* d_ws, size_t ws_size,
                              hipStream_t stream) {
  const float* x   = (const float*)d_in[0];
  const float* W   = (const float*)d_in[1];
  const float* b   = (const float*)d_in[2];
  const float* cre = (const float*)d_in[3];
  const float* cim = (const float*)d_in[4];
  const int* midx  = (const int*)d_in[5];
  const int K = in_sizes[3];
  float* out = (float*)d_out;
  const int chunk = (K + NCHUNK - 1) / NCHUNK;

  char* ws = (char*)d_ws;
  // Layout (peak 20 MB, no live aliasing):
  unsigned* XTb   = (unsigned*)(ws);                             // 0 .. 1.05M
  unsigned* Yp    = (unsigned*)(ws + ((size_t)2 << 20));         // 2M .. 4M
  ushort_t* xbf   = (ushort_t*)(ws + ((size_t)4 << 20));         // 4M .. 5M
  char* meta      = ws + ((size_t)5 << 20);                      // 5M .. 5.03M
  int* tot = (int*)(meta);
  int* off = (int*)(meta + 16384);
  uint2* bucket   = (uint2*)(ws + ((size_t)5 << 20) + 262144);   // 5.25M .. 11.7M
  int* cnt        = (int*)(ws + ((size_t)12 << 20));             // 12M .. 16M
  ushort_t* partb = (ushort_t*)(ws + ((size_t)16 << 20));        // 16M .. 20M

  fused_stage1<<<640, 1024, 0, stream>>>(x, XTb, midx, K, chunk, cnt, xbf);
  colscan<<<16, 256, 0, stream>>>(cnt, tot);
  scan4096<<<1, 1024, 0, stream>>>(tot, off);
  scatter_gemm<<<512, 256, 0, stream>>>(midx, cre, cim, K, chunk, cnt, off, bucket,
                                        xbf, W, partb);
  spmm_col<<<2048, 256, 0, stream>>>(bucket, off, tot, XTb, Yp);
  dft_rows_y<<<dim3(NROW, 2), 1024, 0, stream>>>(Yp, partb, b, out);
}

// Round 16
// 108.588 us; speedup vs baseline: 1.0490x; 1.0490x over previous
//
#include <hip/hip_runtime.h>

// LFMA adapter: out = x@W_base^T + b + x @ (alpha * Re(ifft2(scatter(c, mask_idx))))
// Factored: never materialize Delta_W.
//   X[t,k1] = DFT4096(x rows)      (fused_stage1; Hermitian k<=2048, bf16, dot2 phase2)
//   Y[t,k2] = sum_nz c * X[t,k1]   (spmm in fused_heavy, readlane+dot2)
//   out = SCALE*Re(DFT(Y)) + b + sum(part)   (dft_rows_y, dot2 + fused epilogue)
// R16: back to R13's gemm||spmm fusion (it beat R15's scatter||gemm: 2300 blocks keep
// CUs fed) with the occupancy bug fixed: gemm tile BK=32 -> 16 KB static LDS (was 32,
// which capped ALL fused blocks incl. spmm at 5/CU -> 32% occ). Cost: 4-way LDS read
// conflict on A-fragments (4-slot swizzle) - minority partner, acceptable.
// Bucketing: two-pass LDS-histogram ranking, no global atomics.

#define TWO_PI 6.28318530717958647692f
constexpr int NROW = 128;
constexpr float SCALE_A = 16.0f / 16777216.0f;
constexpr int NCHUNK = 256;
constexpr int KC = 4;

typedef unsigned short ushort_t;
using short8 = __attribute__((ext_vector_type(8))) short;
using f32x4  = __attribute__((ext_vector_type(4))) float;

__device__ __forceinline__ ushort_t f2bf(float f) {
  unsigned u = __float_as_uint(f);
  u = (u + 0x7FFFu + ((u >> 16) & 1u)) >> 16;   // RNE
  return (ushort_t)u;
}
__device__ __forceinline__ unsigned cvtpk(float lo, float hi) {
  unsigned r;
  asm("v_cvt_pk_bf16_f32 %0, %1, %2" : "=v"(r) : "v"(lo), "v"(hi));
  return r;
}
__device__ __forceinline__ float bflo(unsigned u) { return __int_as_float((int)(u << 16)); }
__device__ __forceinline__ float bfhi(unsigned u) { return __int_as_float((int)(u & 0xffff0000u)); }
__device__ __forceinline__ void dot2(float& acc, unsigned a, unsigned b) {
  asm("v_dot2_f32_bf16 %0, %1, %2, %0" : "+v"(acc) : "v"(a), "v"(b));
}
__device__ __forceinline__ void gload_lds16(const void* g, void* l) {
  __builtin_amdgcn_global_load_lds(
      (const __attribute__((address_space(1))) unsigned*)g,
      (__attribute__((address_space(3))) unsigned*)l, 16, 0, 0);
}

// ---------------- stage 1: dft_x (0..255) || count_chunks (256..511) || xcvt (512..639)
__global__ __launch_bounds__(1024) void fused_stage1(const float* __restrict__ x,
                                                     unsigned* __restrict__ XTb,
                                                     const int* __restrict__ idx, int K,
                                                     int chunk, int* __restrict__ cnt,
                                                     ushort_t* __restrict__ xbf) {
  __shared__ __align__(16) char smem[25600];
  const int bx = blockIdx.x, tid = threadIdx.x;
  if (bx >= 512) {                         // ---- xcvt
    int i = (bx - 512) * 1024 + tid;
    float4 v = ((const float4*)x)[i];
    ((uint2*)xbf)[i] = make_uint2(cvtpk(v.x, v.y), cvtpk(v.z, v.w));
    return;
  }
  if (bx < 256) {
    // ---- dft_rows_x: t = bx&127, qi = bx>>7 (k1 residue half)
    float*    xs   = (float*)smem;
    unsigned* bp   = (unsigned*)(smem + 16384);
    float2*   w64f = (float2*)(smem + 24576);
    unsigned* wA   = (unsigned*)(smem + 25088);
    unsigned* wB   = (unsigned*)(smem + 25344);
    const int t = bx & 127, qi = bx >> 7;
    const float* xrow = x + (size_t)t * 4096;
#pragma unroll
    for (int l = 0; l < 4; ++l) xs[tid + 1024 * l] = xrow[tid + 1024 * l];
    if (tid < 64) {
      float s, c; __sincosf(TWO_PI * (float)tid * (1.0f / 64.0f), &s, &c);
      w64f[tid] = make_float2(c, s);
      wA[tid] = cvtpk(c, -s);
      wB[tid] = cvtpk(s, c);
    }
    __syncthreads();
#pragma unroll
    for (int l = 0; l < 2; ++l) {
      int o = tid + 1024 * l, m1 = o >> 5, k1l = o & 31, k1 = qi * 32 + k1l;
      float ar = 0.f, ai = 0.f;
      for (int m2 = 0; m2 < 64; ++m2) {
        float xv = xs[m1 + (m2 << 6)];
        float2 w = w64f[(m2 * k1) & 63];
        ar = fmaf(xv, w.x, ar); ai = fmaf(xv, w.y, ai);
      }
      float s, c; __sincosf((float)(m1 * k1) * (TWO_PI / 4096.0f), &s, &c);
      bp[(m1 << 5) + k1l] = cvtpk(ar * c - ai * s, ar * s + ai * c);
    }
    __syncthreads();
    {
      const int k1l = tid & 31, k2 = tid >> 5;
      const int k = qi * 32 + k1l + (k2 << 6);
      float xr = 0.f, xi = 0.f;
      for (int m1 = 0; m1 < 64; ++m1) {
        unsigned wi = (unsigned)((m1 * k2) & 63);
        unsigned bv = bp[(m1 << 5) + k1l];
        dot2(xr, wA[wi], bv);
        dot2(xi, wB[wi], bv);
      }
      XTb[(size_t)k * NROW + t] = cvtpk(xr, xi);
      if (qi == 0 && tid == 0) {
        float xr2 = 0.f, xi2 = 0.f;
        for (int m1 = 0; m1 < 64; ++m1) {
          float sgn = (m1 & 1) ? -1.f : 1.f;
          unsigned bv = bp[m1 << 5];
          xr2 = fmaf(sgn, bflo(bv), xr2);
          xi2 = fmaf(sgn, bfhi(bv), xi2);
        }
        XTb[(size_t)2048 * NROW + t] = cvtpk(xr2, xi2);
      }
    }
  } else {
    // ---- count_chunks
    int* h = (int*)smem;
    const int c = bx - 256;
#pragma unroll
    for (int l = 0; l < 4; ++l) h[tid + 1024 * l] = 0;
    __syncthreads();
    const int j0 = c * chunk, j1 = min(j0 + chunk, K);
    for (int j = j0 + tid; j < j1; j += 1024) atomicAdd(&h[idx[j] & 4095], 1);
    __syncthreads();
#pragma unroll
    for (int l = 0; l < 4; ++l) cnt[(size_t)c * 4096 + tid + 1024 * l] = h[tid + 1024 * l];
  }
}

// ---------------- S2: per-column exclusive scan over chunks (in place) + totals
__global__ __launch_bounds__(256) void colscan(int* __restrict__ cnt, int* __restrict__ tot) {
  const int k2 = blockIdx.x * 256 + threadIdx.x;
  int run = 0;
  for (int c16 = 0; c16 < NCHUNK; c16 += 16) {
    int v[16];
#pragma unroll
    for (int i = 0; i < 16; ++i) v[i] = cnt[(size_t)(c16 + i) * 4096 + k2];
#pragma unroll
    for (int i = 0; i < 16; ++i) {
      cnt[(size_t)(c16 + i) * 4096 + k2] = run;
      run += v[i];
    }
  }
  tot[k2] = run;
}

// ---------------- B2: exclusive scan over 4096 totals (single block)
__global__ __launch_bounds__(1024) void scan4096(const int* __restrict__ count,
                                                 int* __restrict__ off) {
  __shared__ int s[4096];
  int tid = threadIdx.x;
#pragma unroll
  for (int l = 0; l < 4; ++l) s[tid + 1024 * l] = count[tid + 1024 * l];
  __syncthreads();
  for (int d = 1; d < 4096; d <<= 1) {
    int v[4];
#pragma unroll
    for (int l = 0; l < 4; ++l) {
      int i = tid + 1024 * l;
      v[l] = s[i] + ((i >= d) ? s[i - d] : 0);
    }
    __syncthreads();
#pragma unroll
    for (int l = 0; l < 4; ++l) s[tid + 1024 * l] = v[l];
    __syncthreads();
  }
#pragma unroll
  for (int l = 0; l < 4; ++l) {
    int i = tid + 1024 * l;
    off[i] = s[i] - count[i];
  }
}

// ---------------- S3: scatter with LDS-rank (no returning global atomics)
__global__ __launch_bounds__(1024) void scatter2(const int* __restrict__ idx,
                                                 const float* __restrict__ cre,
                                                 const float* __restrict__ cim, int K,
                                                 int chunk, const int* __restrict__ base,
                                                 const int* __restrict__ off,
                                                 uint2* __restrict__ bucket) {
  __shared__ int lbase[4096];
  __shared__ int lcur[4096];
  const int c = blockIdx.x, tid = threadIdx.x;
#pragma unroll
  for (int l = 0; l < 4; ++l) {
    int k2 = tid + 1024 * l;
    lbase[k2] = base[(size_t)c * 4096 + k2] + off[k2];
    lcur[k2] = 0;
  }
  __syncthreads();
  const int j0 = c * chunk, j1 = min(j0 + chunk, K);
  for (int j = j0 + tid; j < j1; j += 1024) {
    int p = idx[j];
    int k2 = p & 4095;
    int r = atomicAdd(&lcur[k2], 1);
    unsigned cr = f2bf(cre[j]), ci = f2bf(cim[j]);
    bucket[lbase[k2] + r] = make_uint2((unsigned)(p >> 12) | (cr << 16), ci << 16);
  }
}

// ---------------- fused heavy: gemm (blocks 0..255) || spmm (blocks 256..2303)
// gemm: 128x64-tile, BK=32, KC=4 K-split, 16 KB LDS total (un-crushes spmm occ).
__global__ __launch_bounds__(256, 4) void fused_heavy(const uint2* __restrict__ bucket,
                                                      const int* __restrict__ off,
                                                      const int* __restrict__ count,
                                                      const unsigned* __restrict__ XTb,
                                                      unsigned* __restrict__ Yp,
                                                      const ushort_t* __restrict__ xbf,
                                                      const float* __restrict__ W,
                                                      ushort_t* __restrict__ partb) {
  __shared__ __align__(16) char smem[16384];
  const int tid = threadIdx.x;
  const int w = tid >> 6, lane = tid & 63;
  if (blockIdx.x >= 256) {
    // ---------------- spmm ----------------
    float4* red = (float4*)smem;            // [2][64]
    const int colsel = w >> 1, half = w & 1;
    const int k2 = (blockIdx.x - 256) * 2 + colsel;
    const int s = off[k2], n = count[k2];
    const unsigned voff = lane * 8;
    float ar0 = 0.f, ai0 = 0.f, ar1 = 0.f, ai1 = 0.f;
    for (int c = half * 64; c < n; c += 128) {
      int idx = c + lane;
      uint2 ec = (idx < n) ? bucket[s + idx] : make_uint2(0u, 0u);
#pragma unroll
      for (int g = 0; g < 64; g += 8) {
        unsigned Ap[8], Bp[8];
        uint2 xv0, xv1, xv2, xv3, xv4, xv5, xv6, xv7;
#pragma unroll
        for (int u = 0; u < 8; ++u) {
          unsigned w0 = (unsigned)__builtin_amdgcn_readlane((int)ec.x, g + u);
          unsigned w1 = (unsigned)__builtin_amdgcn_readlane((int)ec.y, g + u);
          int k1 = (int)(w0 & 0xfffu);
          unsigned cj = (k1 > 2048) ? 0x8000u : 0u;
          int r = (k1 > 2048) ? 4096 - k1 : k1;
          unsigned cr16 = w0 >> 16;
          unsigned ci16 = w1 >> 16;
          Ap[u] = cr16 | ((ci16 ^ 0x8000u ^ cj) << 16);
          Bp[u] = ci16 | ((cr16 ^ cj) << 16);
          const unsigned* p = XTb + (size_t)r * NROW;
          uint2* dst = (u == 0) ? &xv0 : (u == 1) ? &xv1 : (u == 2) ? &xv2 :
                       (u == 3) ? &xv3 : (u == 4) ? &xv4 : (u == 5) ? &xv5 :
                       (u == 6) ? &xv6 : &xv7;
          asm volatile("global_load_dwordx2 %0, %1, %2"
                       : "=v"(*dst) : "v"(voff), "s"(p) : "memory");
        }
        asm volatile("s_waitcnt vmcnt(0)"
                     : "+v"(xv0), "+v"(xv1), "+v"(xv2), "+v"(xv3),
                       "+v"(xv4), "+v"(xv5), "+v"(xv6), "+v"(xv7) :: "memory");
        __builtin_amdgcn_sched_barrier(0);
#pragma unroll
        for (int u = 0; u < 8; ++u) {
          uint2 xv = (u == 0) ? xv0 : (u == 1) ? xv1 : (u == 2) ? xv2 :
                     (u == 3) ? xv3 : (u == 4) ? xv4 : (u == 5) ? xv5 :
                     (u == 6) ? xv6 : xv7;
          dot2(ar0, Ap[u], xv.x);
          dot2(ai0, Bp[u], xv.x);
          dot2(ar1, Ap[u], xv.y);
          dot2(ai1, Bp[u], xv.y);
        }
      }
    }
    if (half == 1) red[colsel * 64 + lane] = make_float4(ar0, ai0, ar1, ai1);
    __syncthreads();
    if (half == 0) {
      float4 o = red[colsel * 64 + lane];
      ar0 += o.x; ai0 += o.y; ar1 += o.z; ai1 += o.w;
      Yp[(size_t)(2 * lane) * 4096 + k2]     = cvtpk(ar0, ai0);
      Yp[(size_t)(2 * lane + 1) * 4096 + k2] = cvtpk(ar1, ai1);
    }
  } else {
    // ---------------- gemm (BK=32, 16 KB LDS) ----------------
    ushort_t* xs = (ushort_t*)smem;         // [128][32] bf16, 8 KB
    float* wsf = (float*)(smem + 8192);     // [64][32] fp32, 8 KB
    const int f0 = (blockIdx.x & 63) * 64;
    const int kc = blockIdx.x >> 6;
    f32x4 acc[2][4];
#pragma unroll
    for (int i = 0; i < 2; ++i)
#pragma unroll
      for (int j = 0; j < 4; ++j) acc[i][j] = (f32x4){0.f, 0.f, 0.f, 0.f};
    const int kbeg = kc * 1024;
    for (int st = 0; st < 32; ++st) {
      const int k0 = kbeg + st * 32;
      // x tile 8 KB: 2 gload16/wave; LDS linear, global src pre-swizzled (4 slots)
#pragma unroll
      for (int cc = 0; cc < 2; ++cc) {
        int lb = w * 2048 + cc * 1024;
        int e = (lb >> 1) + lane * 8;
        int r = e >> 5, sl = (e >> 3) & 3;
        gload_lds16(xbf + (size_t)r * 4096 + k0 + ((sl ^ (r & 3)) << 3),
                    (char*)xs + lb);
      }
      // W tile fp32 8 KB: 2 gload16/wave
#pragma unroll
      for (int cc = 0; cc < 2; ++cc) {
        int lb = w * 2048 + cc * 1024;
        int e32 = (lb >> 2) + lane * 4;
        int r = e32 >> 5, g = (e32 >> 2) & 7, s8 = g >> 1, h = g & 1;
        gload_lds16(W + (size_t)(f0 + r) * 4096 + k0 + ((s8 ^ (r & 3)) << 3) + (h << 2),
                    (char*)wsf + lb);
      }
      __syncthreads();
      {
        int ksA = lane >> 4;                // 0..3
        short8 af[2], bfr[4];
#pragma unroll
        for (int mf = 0; mf < 2; ++mf) {
          int ra = w * 32 + mf * 16 + (lane & 15);
          af[mf] = *(const short8*)(&xs[ra * 32 + ((ksA ^ (ra & 3)) << 3)]);
        }
#pragma unroll
        for (int nf = 0; nf < 4; ++nf) {
          int rb = nf * 16 + (lane & 15);
          const float* bpp = &wsf[rb * 32 + ((ksA ^ (rb & 3)) << 3)];
          float4 a4 = *(const float4*)bpp;
          float4 b4 = *(const float4*)(bpp + 4);
          union { uint4 u; short8 s; } pk;
          pk.u.x = cvtpk(a4.x, a4.y);
          pk.u.y = cvtpk(a4.z, a4.w);
          pk.u.z = cvtpk(b4.x, b4.y);
          pk.u.w = cvtpk(b4.z, b4.w);
          bfr[nf] = pk.s;
        }
#pragma unroll
        for (int mf = 0; mf < 2; ++mf)
#pragma unroll
          for (int nf = 0; nf < 4; ++nf)
            acc[mf][nf] = __builtin_amdgcn_mfma_f32_16x16x32_bf16(af[mf], bfr[nf], acc[mf][nf], 0, 0, 0);
      }
      __syncthreads();
    }
    ushort_t* pb = partb + ((size_t)kc << 19);
#pragma unroll
    for (int mf = 0; mf < 2; ++mf)
#pragma unroll
      for (int nf = 0; nf < 4; ++nf)
#pragma unroll
        for (int reg = 0; reg < 4; ++reg) {
          int row = w * 32 + mf * 16 + (lane >> 4) * 4 + reg;
          int col = f0 + nf * 16 + (lane & 15);
          pb[(size_t)row * 4096 + col] = f2bf(acc[mf][nf][reg]);
        }
  }
}

// ---------------- out = SCALE*Re(DFT(Yp row)) + bias + sum(bf16 partials). grid (128,2).
__global__ __launch_bounds__(1024) void dft_rows_y(const unsigned* __restrict__ Yp,
                                                   const ushort_t* __restrict__ partb,
                                                   const float* __restrict__ bias,
                                                   float* __restrict__ out) {
  __shared__ unsigned ys[4096];
  __shared__ unsigned bp[2048];
  __shared__ unsigned wA[64], wB[64];
  const int t = blockIdx.x, qi = blockIdx.y, tid = threadIdx.x;
  const unsigned* yrow = Yp + (size_t)t * 4096;
#pragma unroll
  for (int l = 0; l < 4; ++l) ys[tid + 1024 * l] = yrow[tid + 1024 * l];
  if (tid < 64) {
    float s, c; __sincosf(TWO_PI * (float)tid * (1.0f / 64.0f), &s, &c);
    wA[tid] = cvtpk(c, -s);
    wB[tid] = cvtpk(s, c);
  }
  __syncthreads();
#pragma unroll
  for (int l = 0; l < 2; ++l) {
    int o = tid + 1024 * l, a = o >> 5, n1l = o & 31, n1 = qi * 32 + n1l;
    float ar = 0.f, ai = 0.f;
    for (int b = 0; b < 64; ++b) {
      unsigned yv = ys[a + (b << 6)];
      unsigned wi = (unsigned)((n1 * b) & 63);
      dot2(ar, wA[wi], yv);
      dot2(ai, wB[wi], yv);
    }
    float s, c; __sincosf((float)(n1 * a) * (TWO_PI / 4096.0f), &s, &c);
    bp[(a << 5) + n1l] = cvtpk(ar * c - ai * s, ar * s + ai * c);
  }
  __syncthreads();
  float* orow = out + (size_t)t * 4096;
  const int n1l = tid & 31;
  const int n1 = qi * 32 + n1l;
#pragma unroll
  for (int l = 0; l < 2; ++l) {
    int n2 = (tid >> 5) + 32 * l;
    float accv = 0.f;
    for (int a = 0; a < 64; ++a)
      dot2(accv, wA[(unsigned)((n2 * a) & 63)], bp[(a << 5) + n1l]);
    int o = n1 + (n2 << 6);
    float sum = accv * SCALE_A + bias[o];
#pragma unroll
    for (int i = 0; i < KC; ++i)
      sum += __int_as_float((int)((unsigned)partb[((size_t)i << 19) + ((size_t)t << 12) + o] << 16));
    orow[o] = sum;
  }
}

extern "C" void kernel_launch(void* const* d_in, const int* in_sizes, int n_in,
                              void* d_out, int out_size, void* d_ws, size_t ws_size,
                              hipStream_t stream) {
  const float* x   = (const float*)d_in[0];
  const float* W   = (const float*)d_in[1];
  const float* b   = (const float*)d_in[2];
  const float* cre = (const float*)d_in[3];
  const float* cim = (const float*)d_in[4];
  const int* midx  = (const int*)d_in[5];
  const int K = in_sizes[3];
  float* out = (float*)d_out;
  const int chunk = (K + NCHUNK - 1) / NCHUNK;

  char* ws = (char*)d_ws;
  // Layout (peak 20 MB, no live aliasing):
  unsigned* XTb   = (unsigned*)(ws);                             // 0 .. 1.05M
  unsigned* Yp    = (unsigned*)(ws + ((size_t)2 << 20));         // 2M .. 4M
  ushort_t* xbf   = (ushort_t*)(ws + ((size_t)4 << 20));         // 4M .. 5M
  char* meta      = ws + ((size_t)5 << 20);                      // 5M .. 5.03M
  int* tot = (int*)(meta);
  int* off = (int*)(meta + 16384);
  uint2* bucket   = (uint2*)(ws + ((size_t)5 << 20) + 262144);   // 5.25M .. 11.7M
  int* cnt        = (int*)(ws + ((size_t)12 << 20));             // 12M .. 16M
  ushort_t* partb = (ushort_t*)(ws + ((size_t)16 << 20));        // 16M .. 20M

  fused_stage1<<<640, 1024, 0, stream>>>(x, XTb, midx, K, chunk, cnt, xbf);
  colscan<<<16, 256, 0, stream>>>(cnt, tot);
  scan4096<<<1, 1024, 0, stream>>>(tot, off);
  scatter2<<<NCHUNK, 1024, 0, stream>>>(midx, cre, cim, K, chunk, cnt, off, bucket);
  fused_heavy<<<2304, 256, 0, stream>>>(bucket, off, tot, XTb, Yp, xbf, W, partb);
  dft_rows_y<<<dim3(NROW, 2), 1024, 0, stream>>>(Yp, partb, b, out);
}

// Round 17
// 106.339 us; speedup vs baseline: 1.0712x; 1.0211x over previous
//
#include <hip/hip_runtime.h>

// LFMA adapter: out = x@W_base^T + b + x @ (alpha * Re(ifft2(scatter(c, mask_idx))))
// Factored: never materialize Delta_W.
//   X[t,k1] = DFT4096(x rows)      (fused_stage1; Hermitian k<=2048, bf16, dot2 phase2)
//   Y[t,k2] = sum_nz c * X[t,k1]   (spmm in fused_heavy)
//   out = SCALE*Re(DFT(Y)) + b + sum(part)   (dft_rows_y, dot2 + fused epilogue)
// R17: spmm = counted-vmcnt group pipeline (T4). Every prior version drained vmcnt(0)
// per 8-entry group -> full L2 latency exposed + wave convoy (all waves phase-locked).
// Now: issue group g+1's gathers, s_waitcnt vmcnt(8) binding group g's regs, compute g;
// drain only at 128-entry chunk boundaries. Ap/Bp feed dot2 as SGPR src0 (1 SGPR read
// is legal in VOP3P; R14's compile failure was the LOAD's "s" constraint, not this).
// gemm (blocks 0..255, BK=32, 16KB LDS) unchanged; bucketing chain unchanged.

#define TWO_PI 6.28318530717958647692f
constexpr int NROW = 128;
constexpr float SCALE_A = 16.0f / 16777216.0f;
constexpr int NCHUNK = 256;
constexpr int KC = 4;

typedef unsigned short ushort_t;
using short8 = __attribute__((ext_vector_type(8))) short;
using f32x4  = __attribute__((ext_vector_type(4))) float;

__device__ __forceinline__ ushort_t f2bf(float f) {
  unsigned u = __float_as_uint(f);
  u = (u + 0x7FFFu + ((u >> 16) & 1u)) >> 16;   // RNE
  return (ushort_t)u;
}
__device__ __forceinline__ unsigned cvtpk(float lo, float hi) {
  unsigned r;
  asm("v_cvt_pk_bf16_f32 %0, %1, %2" : "=v"(r) : "v"(lo), "v"(hi));
  return r;
}
__device__ __forceinline__ float bflo(unsigned u) { return __int_as_float((int)(u << 16)); }
__device__ __forceinline__ float bfhi(unsigned u) { return __int_as_float((int)(u & 0xffff0000u)); }
__device__ __forceinline__ void dot2(float& acc, unsigned a, unsigned b) {
  asm("v_dot2_f32_bf16 %0, %1, %2, %0" : "+v"(acc) : "v"(a), "v"(b));
}
__device__ __forceinline__ void dot2s(float& acc, unsigned a, unsigned b) {
  asm("v_dot2_f32_bf16 %0, %1, %2, %0" : "+v"(acc) : "s"(a), "v"(b));
}
__device__ __forceinline__ void gload_lds16(const void* g, void* l) {
  __builtin_amdgcn_global_load_lds(
      (const __attribute__((address_space(1))) unsigned*)g,
      (__attribute__((address_space(3))) unsigned*)l, 16, 0, 0);
}

// ---------------- stage 1: dft_x (0..255) || count_chunks (256..511) || xcvt (512..639)
__global__ __launch_bounds__(1024) void fused_stage1(const float* __restrict__ x,
                                                     unsigned* __restrict__ XTb,
                                                     const int* __restrict__ idx, int K,
                                                     int chunk, int* __restrict__ cnt,
                                                     ushort_t* __restrict__ xbf) {
  __shared__ __align__(16) char smem[25600];
  const int bx = blockIdx.x, tid = threadIdx.x;
  if (bx >= 512) {                         // ---- xcvt
    int i = (bx - 512) * 1024 + tid;
    float4 v = ((const float4*)x)[i];
    ((uint2*)xbf)[i] = make_uint2(cvtpk(v.x, v.y), cvtpk(v.z, v.w));
    return;
  }
  if (bx < 256) {
    float*    xs   = (float*)smem;
    unsigned* bp   = (unsigned*)(smem + 16384);
    float2*   w64f = (float2*)(smem + 24576);
    unsigned* wA   = (unsigned*)(smem + 25088);
    unsigned* wB   = (unsigned*)(smem + 25344);
    const int t = bx & 127, qi = bx >> 7;
    const float* xrow = x + (size_t)t * 4096;
#pragma unroll
    for (int l = 0; l < 4; ++l) xs[tid + 1024 * l] = xrow[tid + 1024 * l];
    if (tid < 64) {
      float s, c; __sincosf(TWO_PI * (float)tid * (1.0f / 64.0f), &s, &c);
      w64f[tid] = make_float2(c, s);
      wA[tid] = cvtpk(c, -s);
      wB[tid] = cvtpk(s, c);
    }
    __syncthreads();
#pragma unroll
    for (int l = 0; l < 2; ++l) {
      int o = tid + 1024 * l, m1 = o >> 5, k1l = o & 31, k1 = qi * 32 + k1l;
      float ar = 0.f, ai = 0.f;
      for (int m2 = 0; m2 < 64; ++m2) {
        float xv = xs[m1 + (m2 << 6)];
        float2 w = w64f[(m2 * k1) & 63];
        ar = fmaf(xv, w.x, ar); ai = fmaf(xv, w.y, ai);
      }
      float s, c; __sincosf((float)(m1 * k1) * (TWO_PI / 4096.0f), &s, &c);
      bp[(m1 << 5) + k1l] = cvtpk(ar * c - ai * s, ar * s + ai * c);
    }
    __syncthreads();
    {
      const int k1l = tid & 31, k2 = tid >> 5;
      const int k = qi * 32 + k1l + (k2 << 6);
      float xr = 0.f, xi = 0.f;
      for (int m1 = 0; m1 < 64; ++m1) {
        unsigned wi = (unsigned)((m1 * k2) & 63);
        unsigned bv = bp[(m1 << 5) + k1l];
        dot2(xr, wA[wi], bv);
        dot2(xi, wB[wi], bv);
      }
      XTb[(size_t)k * NROW + t] = cvtpk(xr, xi);
      if (qi == 0 && tid == 0) {
        float xr2 = 0.f, xi2 = 0.f;
        for (int m1 = 0; m1 < 64; ++m1) {
          float sgn = (m1 & 1) ? -1.f : 1.f;
          unsigned bv = bp[m1 << 5];
          xr2 = fmaf(sgn, bflo(bv), xr2);
          xi2 = fmaf(sgn, bfhi(bv), xi2);
        }
        XTb[(size_t)2048 * NROW + t] = cvtpk(xr2, xi2);
      }
    }
  } else {
    int* h = (int*)smem;
    const int c = bx - 256;
#pragma unroll
    for (int l = 0; l < 4; ++l) h[tid + 1024 * l] = 0;
    __syncthreads();
    const int j0 = c * chunk, j1 = min(j0 + chunk, K);
    for (int j = j0 + tid; j < j1; j += 1024) atomicAdd(&h[idx[j] & 4095], 1);
    __syncthreads();
#pragma unroll
    for (int l = 0; l < 4; ++l) cnt[(size_t)c * 4096 + tid + 1024 * l] = h[tid + 1024 * l];
  }
}

// ---------------- S2: per-column exclusive scan over chunks (in place) + totals
__global__ __launch_bounds__(256) void colscan(int* __restrict__ cnt, int* __restrict__ tot) {
  const int k2 = blockIdx.x * 256 + threadIdx.x;
  int run = 0;
  for (int c16 = 0; c16 < NCHUNK; c16 += 16) {
    int v[16];
#pragma unroll
    for (int i = 0; i < 16; ++i) v[i] = cnt[(size_t)(c16 + i) * 4096 + k2];
#pragma unroll
    for (int i = 0; i < 16; ++i) {
      cnt[(size_t)(c16 + i) * 4096 + k2] = run;
      run += v[i];
    }
  }
  tot[k2] = run;
}

// ---------------- B2: exclusive scan over 4096 totals (single block)
__global__ __launch_bounds__(1024) void scan4096(const int* __restrict__ count,
                                                 int* __restrict__ off) {
  __shared__ int s[4096];
  int tid = threadIdx.x;
#pragma unroll
  for (int l = 0; l < 4; ++l) s[tid + 1024 * l] = count[tid + 1024 * l];
  __syncthreads();
  for (int d = 1; d < 4096; d <<= 1) {
    int v[4];
#pragma unroll
    for (int l = 0; l < 4; ++l) {
      int i = tid + 1024 * l;
      v[l] = s[i] + ((i >= d) ? s[i - d] : 0);
    }
    __syncthreads();
#pragma unroll
    for (int l = 0; l < 4; ++l) s[tid + 1024 * l] = v[l];
    __syncthreads();
  }
#pragma unroll
  for (int l = 0; l < 4; ++l) {
    int i = tid + 1024 * l;
    off[i] = s[i] - count[i];
  }
}

// ---------------- S3: scatter with LDS-rank (no returning global atomics)
__global__ __launch_bounds__(1024) void scatter2(const int* __restrict__ idx,
                                                 const float* __restrict__ cre,
                                                 const float* __restrict__ cim, int K,
                                                 int chunk, const int* __restrict__ base,
                                                 const int* __restrict__ off,
                                                 uint2* __restrict__ bucket) {
  __shared__ int lbase[4096];
  __shared__ int lcur[4096];
  const int c = blockIdx.x, tid = threadIdx.x;
#pragma unroll
  for (int l = 0; l < 4; ++l) {
    int k2 = tid + 1024 * l;
    lbase[k2] = base[(size_t)c * 4096 + k2] + off[k2];
    lcur[k2] = 0;
  }
  __syncthreads();
  const int j0 = c * chunk, j1 = min(j0 + chunk, K);
  for (int j = j0 + tid; j < j1; j += 1024) {
    int p = idx[j];
    int k2 = p & 4095;
    int r = atomicAdd(&lcur[k2], 1);
    unsigned cr = f2bf(cre[j]), ci = f2bf(cim[j]);
    bucket[lbase[k2] + r] = make_uint2((unsigned)(p >> 12) | (cr << 16), ci << 16);
  }
}

// ---- spmm pipeline macros: fold entry (g*8+u) on SALU, issue gather; counted waits.
#define SP_ISS1(g, u, AP, BP, XV) { \
    unsigned w0_ = (unsigned)__builtin_amdgcn_readlane((int)ec.x, (g) * 8 + (u)); \
    unsigned w1_ = (unsigned)__builtin_amdgcn_readlane((int)ec.y, (g) * 8 + (u)); \
    int k1_ = (int)(w0_ & 0xfffu); \
    unsigned cj_ = (k1_ > 2048) ? 0x8000u : 0u; \
    int r_ = (k1_ > 2048) ? 4096 - k1_ : k1_; \
    AP[u] = (w0_ >> 16) | ((((w1_ >> 16) ^ 0x8000u ^ cj_)) << 16); \
    BP[u] = (w1_ >> 16) | ((((w0_ >> 16) ^ cj_)) << 16); \
    const unsigned* p_ = XTb + (size_t)r_ * NROW; \
    asm volatile("global_load_dwordx2 %0, %1, %2" \
                 : "=v"(XV) : "v"(voff), "s"(p_) : "memory"); }
#define SP_ISS8(g, AP, BP, X) \
    SP_ISS1(g, 0, AP, BP, X##0) SP_ISS1(g, 1, AP, BP, X##1) \
    SP_ISS1(g, 2, AP, BP, X##2) SP_ISS1(g, 3, AP, BP, X##3) \
    SP_ISS1(g, 4, AP, BP, X##4) SP_ISS1(g, 5, AP, BP, X##5) \
    SP_ISS1(g, 6, AP, BP, X##6) SP_ISS1(g, 7, AP, BP, X##7)
#define SP_WAIT8(X) \
    asm volatile("s_waitcnt vmcnt(8)" \
                 : "+v"(X##0), "+v"(X##1), "+v"(X##2), "+v"(X##3), \
                   "+v"(X##4), "+v"(X##5), "+v"(X##6), "+v"(X##7) :: "memory"); \
    __builtin_amdgcn_sched_barrier(0);
#define SP_WAIT0(X) \
    asm volatile("s_waitcnt vmcnt(0)" \
                 : "+v"(X##0), "+v"(X##1), "+v"(X##2), "+v"(X##3), \
                   "+v"(X##4), "+v"(X##5), "+v"(X##6), "+v"(X##7) :: "memory"); \
    __builtin_amdgcn_sched_barrier(0);
#define SP_CMP1(u, AP, BP, XV) \
    dot2s(ar0, AP[u], XV.x); dot2s(ai0, BP[u], XV.x); \
    dot2s(ar1, AP[u], XV.y); dot2s(ai1, BP[u], XV.y);
#define SP_CMP8(AP, BP, X) \
    SP_CMP1(0, AP, BP, X##0) SP_CMP1(1, AP, BP, X##1) \
    SP_CMP1(2, AP, BP, X##2) SP_CMP1(3, AP, BP, X##3) \
    SP_CMP1(4, AP, BP, X##4) SP_CMP1(5, AP, BP, X##5) \
    SP_CMP1(6, AP, BP, X##6) SP_CMP1(7, AP, BP, X##7)

// ---------------- fused heavy: gemm (blocks 0..255) || spmm (blocks 256..2303)
__global__ __launch_bounds__(256, 4) void fused_heavy(const uint2* __restrict__ bucket,
                                                      const int* __restrict__ off,
                                                      const int* __restrict__ count,
                                                      const unsigned* __restrict__ XTb,
                                                      unsigned* __restrict__ Yp,
                                                      const ushort_t* __restrict__ xbf,
                                                      const float* __restrict__ W,
                                                      ushort_t* __restrict__ partb) {
  __shared__ __align__(16) char smem[16384];
  const int tid = threadIdx.x;
  const int w = tid >> 6, lane = tid & 63;
  if (blockIdx.x >= 256) {
    // ---------------- spmm: counted-vmcnt double-buffered pipeline ----------------
    float4* red = (float4*)smem;
    const int colsel = w >> 1, half = w & 1;
    const int k2 = (blockIdx.x - 256) * 2 + colsel;
    const int s = off[k2], n = count[k2];
    const unsigned voff = lane * 8;
    float ar0 = 0.f, ai0 = 0.f, ar1 = 0.f, ai1 = 0.f;
    for (int c = half * 64; c < n; c += 128) {
      int idx = c + lane;
      uint2 ec = (idx < n) ? bucket[s + idx] : make_uint2(0u, 0u);
      unsigned ApA[8], BpA[8], ApB[8], BpB[8];
      uint2 xa0, xa1, xa2, xa3, xa4, xa5, xa6, xa7;
      uint2 xb0, xb1, xb2, xb3, xb4, xb5, xb6, xb7;
      SP_ISS8(0, ApA, BpA, xa)
      SP_ISS8(1, ApB, BpB, xb)
      SP_WAIT8(xa) SP_CMP8(ApA, BpA, xa)
      SP_ISS8(2, ApA, BpA, xa)
      SP_WAIT8(xb) SP_CMP8(ApB, BpB, xb)
      SP_ISS8(3, ApB, BpB, xb)
      SP_WAIT8(xa) SP_CMP8(ApA, BpA, xa)
      SP_ISS8(4, ApA, BpA, xa)
      SP_WAIT8(xb) SP_CMP8(ApB, BpB, xb)
      SP_ISS8(5, ApB, BpB, xb)
      SP_WAIT8(xa) SP_CMP8(ApA, BpA, xa)
      SP_ISS8(6, ApA, BpA, xa)
      SP_WAIT8(xb) SP_CMP8(ApB, BpB, xb)
      SP_ISS8(7, ApB, BpB, xb)
      SP_WAIT8(xa) SP_CMP8(ApA, BpA, xa)
      SP_WAIT0(xb) SP_CMP8(ApB, BpB, xb)
    }
    if (half == 1) red[colsel * 64 + lane] = make_float4(ar0, ai0, ar1, ai1);
    __syncthreads();
    if (half == 0) {
      float4 o = red[colsel * 64 + lane];
      ar0 += o.x; ai0 += o.y; ar1 += o.z; ai1 += o.w;
      Yp[(size_t)(2 * lane) * 4096 + k2]     = cvtpk(ar0, ai0);
      Yp[(size_t)(2 * lane + 1) * 4096 + k2] = cvtpk(ar1, ai1);
    }
  } else {
    // ---------------- gemm (BK=32, 16 KB LDS) ----------------
    ushort_t* xs = (ushort_t*)smem;         // [128][32] bf16, 8 KB
    float* wsf = (float*)(smem + 8192);     // [64][32] fp32, 8 KB
    const int f0 = (blockIdx.x & 63) * 64;
    const int kc = blockIdx.x >> 6;
    f32x4 acc[2][4];
#pragma unroll
    for (int i = 0; i < 2; ++i)
#pragma unroll
      for (int j = 0; j < 4; ++j) acc[i][j] = (f32x4){0.f, 0.f, 0.f, 0.f};
    const int kbeg = kc * 1024;
    for (int st = 0; st < 32; ++st) {
      const int k0 = kbeg + st * 32;
#pragma unroll
      for (int cc = 0; cc < 2; ++cc) {
        int lb = w * 2048 + cc * 1024;
        int e = (lb >> 1) + lane * 8;
        int r = e >> 5, sl = (e >> 3) & 3;
        gload_lds16(xbf + (size_t)r * 4096 + k0 + ((sl ^ (r & 3)) << 3),
                    (char*)xs + lb);
      }
#pragma unroll
      for (int cc = 0; cc < 2; ++cc) {
        int lb = w * 2048 + cc * 1024;
        int e32 = (lb >> 2) + lane * 4;
        int r = e32 >> 5, g = (e32 >> 2) & 7, s8 = g >> 1, h = g & 1;
        gload_lds16(W + (size_t)(f0 + r) * 4096 + k0 + ((s8 ^ (r & 3)) << 3) + (h << 2),
                    (char*)wsf + lb);
      }
      __syncthreads();
      {
        int ksA = lane >> 4;
        short8 af[2], bfr[4];
#pragma unroll
        for (int mf = 0; mf < 2; ++mf) {
          int ra = w * 32 + mf * 16 + (lane & 15);
          af[mf] = *(const short8*)(&xs[ra * 32 + ((ksA ^ (ra & 3)) << 3)]);
        }
#pragma unroll
        for (int nf = 0; nf < 4; ++nf) {
          int rb = nf * 16 + (lane & 15);
          const float* bpp = &wsf[rb * 32 + ((ksA ^ (rb & 3)) << 3)];
          float4 a4 = *(const float4*)bpp;
          float4 b4 = *(const float4*)(bpp + 4);
          union { uint4 u; short8 s; } pk;
          pk.u.x = cvtpk(a4.x, a4.y);
          pk.u.y = cvtpk(a4.z, a4.w);
          pk.u.z = cvtpk(b4.x, b4.y);
          pk.u.w = cvtpk(b4.z, b4.w);
          bfr[nf] = pk.s;
        }
#pragma unroll
        for (int mf = 0; mf < 2; ++mf)
#pragma unroll
          for (int nf = 0; nf < 4; ++nf)
            acc[mf][nf] = __builtin_amdgcn_mfma_f32_16x16x32_bf16(af[mf], bfr[nf], acc[mf][nf], 0, 0, 0);
      }
      __syncthreads();
    }
    ushort_t* pb = partb + ((size_t)kc << 19);
#pragma unroll
    for (int mf = 0; mf < 2; ++mf)
#pragma unroll
      for (int nf = 0; nf < 4; ++nf)
#pragma unroll
        for (int reg = 0; reg < 4; ++reg) {
          int row = w * 32 + mf * 16 + (lane >> 4) * 4 + reg;
          int col = f0 + nf * 16 + (lane & 15);
          pb[(size_t)row * 4096 + col] = f2bf(acc[mf][nf][reg]);
        }
  }
}

// ---------------- out = SCALE*Re(DFT(Yp row)) + bias + sum(bf16 partials). grid (128,2).
__global__ __launch_bounds__(1024) void dft_rows_y(const unsigned* __restrict__ Yp,
                                                   const ushort_t* __restrict__ partb,
                                                   const float* __restrict__ bias,
                                                   float* __restrict__ out) {
  __shared__ unsigned ys[4096];
  __shared__ unsigned bp[2048];
  __shared__ unsigned wA[64], wB[64];
  const int t = blockIdx.x, qi = blockIdx.y, tid = threadIdx.x;
  const unsigned* yrow = Yp + (size_t)t * 4096;
#pragma unroll
  for (int l = 0; l < 4; ++l) ys[tid + 1024 * l] = yrow[tid + 1024 * l];
  if (tid < 64) {
    float s, c; __sincosf(TWO_PI * (float)tid * (1.0f / 64.0f), &s, &c);
    wA[tid] = cvtpk(c, -s);
    wB[tid] = cvtpk(s, c);
  }
  __syncthreads();
#pragma unroll
  for (int l = 0; l < 2; ++l) {
    int o = tid + 1024 * l, a = o >> 5, n1l = o & 31, n1 = qi * 32 + n1l;
    float ar = 0.f, ai = 0.f;
    for (int b = 0; b < 64; ++b) {
      unsigned yv = ys[a + (b << 6)];
      unsigned wi = (unsigned)((n1 * b) & 63);
      dot2(ar, wA[wi], yv);
      dot2(ai, wB[wi], yv);
    }
    float s, c; __sincosf((float)(n1 * a) * (TWO_PI / 4096.0f), &s, &c);
    bp[(a << 5) + n1l] = cvtpk(ar * c - ai * s, ar * s + ai * c);
  }
  __syncthreads();
  float* orow = out + (size_t)t * 4096;
  const int n1l = tid & 31;
  const int n1 = qi * 32 + n1l;
#pragma unroll
  for (int l = 0; l < 2; ++l) {
    int n2 = (tid >> 5) + 32 * l;
    float accv = 0.f;
    for (int a = 0; a < 64; ++a)
      dot2(accv, wA[(unsigned)((n2 * a) & 63)], bp[(a << 5) + n1l]);
    int o = n1 + (n2 << 6);
    float sum = accv * SCALE_A + bias[o];
#pragma unroll
    for (int i = 0; i < KC; ++i)
      sum += __int_as_float((int)((unsigned)partb[((size_t)i << 19) + ((size_t)t << 12) + o] << 16));
    orow[o] = sum;
  }
}

extern "C" void kernel_launch(void* const* d_in, const int* in_sizes, int n_in,
                              void* d_out, int out_size, void* d_ws, size_t ws_size,
                              hipStream_t stream) {
  const float* x   = (const float*)d_in[0];
  const float* W   = (const float*)d_in[1];
  const float* b   = (const float*)d_in[2];
  const float* cre = (const float*)d_in[3];
  const float* cim = (const float*)d_in[4];
  const int* midx  = (const int*)d_in[5];
  const int K = in_sizes[3];
  float* out = (float*)d_out;
  const int chunk = (K + NCHUNK - 1) / NCHUNK;

  char* ws = (char*)d_ws;
  // Layout (peak 20 MB, no live aliasing):
  unsigned* XTb   = (unsigned*)(ws);                             // 0 .. 1.05M
  unsigned* Yp    = (unsigned*)(ws + ((size_t)2 << 20));         // 2M .. 4M
  ushort_t* xbf   = (ushort_t*)(ws + ((size_t)4 << 20));         // 4M .. 5M
  char* meta      = ws + ((size_t)5 << 20);                      // 5M .. 5.03M
  int* tot = (int*)(meta);
  int* off = (int*)(meta + 16384);
  uint2* bucket   = (uint2*)(ws + ((size_t)5 << 20) + 262144);   // 5.25M .. 11.7M
  int* cnt        = (int*)(ws + ((size_t)12 << 20));             // 12M .. 16M
  ushort_t* partb = (ushort_t*)(ws + ((size_t)16 << 20));        // 16M .. 20M

  fused_stage1<<<640, 1024, 0, stream>>>(x, XTb, midx, K, chunk, cnt, xbf);
  colscan<<<16, 256, 0, stream>>>(cnt, tot);
  scan4096<<<1, 1024, 0, stream>>>(tot, off);
  scatter2<<<NCHUNK, 1024, 0, stream>>>(midx, cre, cim, K, chunk, cnt, off, bucket);
  fused_heavy<<<2304, 256, 0, stream>>>(bucket, off, tot, XTb, Yp, xbf, W, partb);
  dft_rows_y<<<dim3(NROW, 2), 1024, 0, stream>>>(Yp, partb, b, out);
}